// Round 3
// baseline (482.666 us; speedup 1.0000x reference)
//
#include <hip/hip_runtime.h>

typedef __bf16 bf16x8 __attribute__((ext_vector_type(8)));
typedef __bf16 bf16x4 __attribute__((ext_vector_type(4)));
typedef float  f32x4  __attribute__((ext_vector_type(4)));

#define MFMA16(a, b, c) __builtin_amdgcn_mfma_f32_16x16x32_bf16((a), (b), (c), 0, 0, 0)

constexpr int N_ = 8, H_ = 8, S_ = 1024, D_ = 64;

// ---------------------------------------------------------------------------
// Kernel 1: per-head projections (unchanged — known good).
// ---------------------------------------------------------------------------
__global__ __launch_bounds__(256) void proj_kernel(
    const float* __restrict__ Xq, const float* __restrict__ Xk,
    const float* __restrict__ Xv,
    const float* __restrict__ Wq, const float* __restrict__ Wk,
    const float* __restrict__ Wv,
    unsigned short* __restrict__ qb_, unsigned short* __restrict__ kb_,
    unsigned short* __restrict__ vtb_)
{
    __shared__ __bf16 T[64 * 72];            // 9.2 KB staging tile

    const int which = blockIdx.y;
    const float* X = (which == 0) ? Xq : (which == 1) ? Xk : Xv;
    const float* W = (which == 0) ? Wq : (which == 1) ? Wk : Wv;

    const int b   = blockIdx.x;              // 0..1023
    const int st  = b & 15;
    const int h   = (b >> 4) & 7;
    const int n   = b >> 7;
    const int s0  = st * 64;
    const int nh  = n * H_ + h;
    const int tid = threadIdx.x;
    const int w = tid >> 6, lane = tid & 63;
    const int l16 = lane & 15, quad = lane >> 4;

    const float* xrow = X + (size_t)(n * S_ + s0 + w * 16 + l16) * D_;
    bf16x8 a[2];
#pragma unroll
    for (int half = 0; half < 2; ++half) {
        const float* p = xrow + half * 32 + quad * 8;
        f32x4 x0 = *(const f32x4*)p;
        f32x4 x1 = *(const f32x4*)(p + 4);
#pragma unroll
        for (int j = 0; j < 4; ++j) { a[half][j] = (__bf16)x0[j]; a[half][4 + j] = (__bf16)x1[j]; }
    }

#pragma unroll
    for (int et = 0; et < 4; ++et) {
        const int e0 = et * 16;
        f32x4 acc = {0.f, 0.f, 0.f, 0.f};
#pragma unroll
        for (int half = 0; half < 2; ++half) {
            const float* wp = W + ((size_t)(h * 64 + e0 + l16)) * 64 + half * 32 + quad * 8;
            f32x4 x0 = *(const f32x4*)wp;
            f32x4 x1 = *(const f32x4*)(wp + 4);
            bf16x8 bf;
#pragma unroll
            for (int j = 0; j < 4; ++j) { bf[j] = (__bf16)x0[j]; bf[4 + j] = (__bf16)x1[j]; }
            acc = MFMA16(a[half], bf, acc);
        }
#pragma unroll
        for (int r = 0; r < 4; ++r) {
            const int sl = w * 16 + quad * 4 + r;
            const int e  = e0 + l16;
            const __bf16 v = (__bf16)acc[r];
            if (which == 2) T[e * 72 + sl] = v;     // transposed tile [e][s]
            else            T[sl * 72 + e] = v;     // [s][e]
        }
    }
    __syncthreads();

    const int row = tid >> 2, seg = tid & 3;
    const bf16x8 d0 = *(const bf16x8*)&T[row * 72 + seg * 16];
    const bf16x8 d1 = *(const bf16x8*)&T[row * 72 + seg * 16 + 8];
    __bf16* dst;
    if (which == 2)
        dst = (__bf16*)vtb_ + ((size_t)nh * 64 + row) * S_ + s0 + seg * 16;
    else
        dst = (__bf16*)(which == 0 ? qb_ : kb_) + ((size_t)nh * S_ + s0 + row) * D_ + seg * 16;
    *(bf16x8*)dst = d0;
    *(bf16x8*)(dst + 8) = d1;
}

// ---------------------------------------------------------------------------
// Kernel 2: attention.  Round-2 bpermute pipeline kept; parallelism doubled
// and XCD locality fixed:
//   * grid 2048 (8 blocks/CU -> 32 waves/CU), block = 32 q-rows.
//   * 2-way K-split: waves {0,1} keys [0,512), waves {2,3} keys [512,1024);
//     denominator + PV partials joined via two small LDS exchanges (no
//     inner-loop barriers).
//   * bijective XCD swizzle: all 32 blocks of a head land on one XCD ->
//     per-XCD K/V working set 8 heads x 256 KB = 2 MB, L2-resident.
// ---------------------------------------------------------------------------
__global__ __launch_bounds__(256, 8) void attn_kernel(
    const unsigned short* __restrict__ qb_, const unsigned short* __restrict__ kb_,
    const unsigned short* __restrict__ vtb_,
    float* __restrict__ attn_out, unsigned short* __restrict__ catb_)
{
    __shared__ float Sred[4 * 16];           // per-wave partial denominators
    __shared__ float Ored[2 * 16 * 68];      // kw=1 waves' PV partials (8.7 KB)

    const __bf16* qb  = (const __bf16*)qb_;
    const __bf16* kb  = (const __bf16*)kb_;
    const __bf16* vtb = (const __bf16*)vtb_;
    __bf16* catb = (__bf16*)catb_;

    // XCD swizzle: consecutive hardware blocks round-robin XCDs; remap so
    // XCD x gets logical blocks [x*256, (x+1)*256) = 8 whole heads.
    const int bid = blockIdx.x;              // 0..2047
    const int b   = (bid & 7) * 256 + (bid >> 3);
    const int qt  = b & 31;
    const int h   = (b >> 5) & 7;
    const int n   = b >> 8;
    const int nh  = n * H_ + h;
    const int q0  = qt * 32;

    const int tid = threadIdx.x;
    const int w = tid >> 6, lane = tid & 63;
    const int l16 = lane & 15, quad = lane >> 4;
    const int rw = w & 1;                    // row half (0: rows 0-15, 1: 16-31)
    const int kw = w >> 1;                   // key half
    const int k0 = kw * 512;

    // persistent Q fragments (row q0 + rw*16 + l16, two embed-halves)
    const __bf16* qbase = qb + ((size_t)(nh * S_ + q0 + rw * 16 + l16)) * D_;
    const bf16x8 aq0 = *(const bf16x8*)(qbase + quad * 8);
    const bf16x8 aq1 = *(const bf16x8*)(qbase + 32 + quad * 8);

    const __bf16* kbase = kb + ((size_t)(nh * S_ + k0 + l16)) * D_ + quad * 8;

    // ---- pass 1: partial row sums of exp(qk/8) over this wave's 512 keys.
    // Swapped MFMA: per-lane partial covers keys {k0 + 16kt + 4quad + r}, q=l16.
    float ssum = 0.f;
#pragma unroll 4
    for (int kt = 0; kt < 32; ++kt) {
        const __bf16* kp = kbase + (size_t)kt * 16 * D_;
        const bf16x8 b0 = *(const bf16x8*)kp;
        const bf16x8 b1 = *(const bf16x8*)(kp + 32);
        f32x4 c = {0.f, 0.f, 0.f, 0.f};
        c = MFMA16(b0, aq0, c);
        c = MFMA16(b1, aq1, c);
#pragma unroll
        for (int r = 0; r < 4; ++r) ssum += __expf(c[r] * 0.125f);
    }
    // reduce across the 4 quads (same l16 = same q-row)
    ssum += __shfl_xor(ssum, 16);
    ssum += __shfl_xor(ssum, 32);
    if (lane < 16) Sred[w * 16 + lane] = ssum;
    __syncthreads();
    const float inv = 1.0f / (Sred[w * 16 + l16] + Sred[(w ^ 2) * 16 + l16]);

    // ---- pass 2: recompute QK, in-register transpose, attn store, partial PV
    float* abase = attn_out + ((size_t)(nh * S_ + q0 + rw * 16 + l16)) * S_ + k0;
    const __bf16* vbase = vtb + ((size_t)(nh * 64 + l16)) * S_ + k0 + quad * 8;

    const int lo_addr = (((quad & 1) * 2) * 16 + l16) * 4;
    const int hi_addr = lo_addr + 64;
    const bool hiq = (quad & 2) != 0;        // target tile = quad>>1

    f32x4 acc[4] = {{0.f,0.f,0.f,0.f},{0.f,0.f,0.f,0.f},{0.f,0.f,0.f,0.f},{0.f,0.f,0.f,0.f}};

#pragma unroll 2
    for (int ch = 0; ch < 16; ++ch) {
        unsigned Wt[2][2];
#pragma unroll
        for (int t = 0; t < 2; ++t) {
            const int kt = ch * 2 + t;
            const __bf16* kp = kbase + (size_t)kt * 16 * D_;
            const bf16x8 b0 = *(const bf16x8*)kp;
            const bf16x8 b1 = *(const bf16x8*)(kp + 32);
            f32x4 c = {0.f, 0.f, 0.f, 0.f};
            c = MFMA16(b0, aq0, c);
            c = MFMA16(b1, aq1, c);
            float p[4];
#pragma unroll
            for (int r = 0; r < 4; ++r) p[r] = __expf(c[r] * 0.125f) * inv;
#pragma unroll
            for (int pr = 0; pr < 2; ++pr) {
                const __bf16 ha = (__bf16)p[2 * pr], hb = (__bf16)p[2 * pr + 1];
                const unsigned ua = *(const unsigned short*)&ha;
                const unsigned ub = *(const unsigned short*)&hb;
                Wt[t][pr] = ua | (ub << 16);
            }
        }
        // in-register transpose: build PV A-fragment P[q=l16][k=quad*8+j]
        const int s00 = __builtin_amdgcn_ds_bpermute(lo_addr, (int)Wt[0][0]);
        const int s10 = __builtin_amdgcn_ds_bpermute(lo_addr, (int)Wt[1][0]);
        const int s01 = __builtin_amdgcn_ds_bpermute(lo_addr, (int)Wt[0][1]);
        const int s11 = __builtin_amdgcn_ds_bpermute(lo_addr, (int)Wt[1][1]);
        const int s02 = __builtin_amdgcn_ds_bpermute(hi_addr, (int)Wt[0][0]);
        const int s12 = __builtin_amdgcn_ds_bpermute(hi_addr, (int)Wt[1][0]);
        const int s03 = __builtin_amdgcn_ds_bpermute(hi_addr, (int)Wt[0][1]);
        const int s13 = __builtin_amdgcn_ds_bpermute(hi_addr, (int)Wt[1][1]);
        union { bf16x8 v; unsigned u[4]; } pf;
        pf.u[0] = (unsigned)(hiq ? s10 : s00);
        pf.u[1] = (unsigned)(hiq ? s11 : s01);
        pf.u[2] = (unsigned)(hiq ? s12 : s02);
        pf.u[3] = (unsigned)(hiq ? s13 : s03);

        // PV: acc[et] += P(16x32) * V(32x16)
#pragma unroll
        for (int et = 0; et < 4; ++et) {
            const bf16x8 bv = *(const bf16x8*)(vbase + (size_t)et * 16 * S_ + ch * 32);
            acc[et] = MFMA16(pf.v, bv, acc[et]);
        }

        // attn fp32 store: row q0+rw*16+l16, cols k0+ch*32+quad*8 (2x16B);
        // one chunk writes a full 128B line per row.
        f32x4 f0, f1;
#pragma unroll
        for (int j = 0; j < 4; ++j) { f0[j] = (float)pf.v[j]; f1[j] = (float)pf.v[4 + j]; }
        float* ap = abase + ch * 32 + quad * 8;
        *(f32x4*)ap = f0;
        *(f32x4*)(ap + 4) = f1;
    }

    // ---- cross-wave PV reduction: kw=1 waves publish, kw=0 waves finish ----
    __syncthreads();                          // Sred fully consumed before reuse
    if (kw == 1) {
#pragma unroll
        for (int et = 0; et < 4; ++et)
#pragma unroll
            for (int r = 0; r < 4; ++r)
                Ored[rw * (16 * 68) + (quad * 4 + r) * 68 + et * 16 + l16] = acc[et][r];
    }
    __syncthreads();
    if (kw == 0) {
#pragma unroll
        for (int r = 0; r < 4; ++r) {
            const int s = q0 + rw * 16 + quad * 4 + r;
            __bf16* cp = catb + ((size_t)n * S_ + s) * (H_ * D_) + h * D_ + l16;
#pragma unroll
            for (int et = 0; et < 4; ++et) {
                const float o = acc[et][r] +
                    Ored[rw * (16 * 68) + (quad * 4 + r) * 68 + et * 16 + l16];
                cp[et * 16] = (__bf16)o;
            }
        }
    }
}

// ---------------------------------------------------------------------------
// Kernel 3: out = cat @ Wout^T + bout.  (unchanged — known good)
// ---------------------------------------------------------------------------
__global__ __launch_bounds__(256) void outproj_kernel(
    const unsigned short* __restrict__ catb_, const float* __restrict__ Wout,
    const float* __restrict__ bout, float* __restrict__ out)
{
    __shared__ float R[4 * 16 * 68];         // 17.4 KB partials

    const __bf16* catb = (const __bf16*)catb_;
    const int r0  = blockIdx.x * 16;
    const int tid = threadIdx.x;
    const int w = tid >> 6, lane = tid & 63;
    const int l16 = lane & 15, quad = lane >> 4;
    const int k0 = w * 128;

    const __bf16* arow  = catb + (size_t)(r0 + l16) * 512 + k0 + quad * 8;
    const float*  wbase = Wout + (size_t)l16 * 512 + k0 + quad * 8;

    f32x4 acc[4] = {{0.f,0.f,0.f,0.f},{0.f,0.f,0.f,0.f},{0.f,0.f,0.f,0.f},{0.f,0.f,0.f,0.f}};

#pragma unroll
    for (int kc = 0; kc < 4; ++kc) {
        const bf16x8 af = *(const bf16x8*)(arow + kc * 32);
#pragma unroll
        for (int et = 0; et < 4; ++et) {
            const float* wp = wbase + (size_t)et * 16 * 512 + kc * 32;
            f32x4 x0 = *(const f32x4*)wp;
            f32x4 x1 = *(const f32x4*)(wp + 4);
            bf16x8 bf;
#pragma unroll
            for (int j = 0; j < 4; ++j) { bf[j] = (__bf16)x0[j]; bf[4 + j] = (__bf16)x1[j]; }
            acc[et] = MFMA16(af, bf, acc[et]);
        }
    }
#pragma unroll
    for (int et = 0; et < 4; ++et)
#pragma unroll
        for (int r = 0; r < 4; ++r)
            R[w * (16 * 68) + (quad * 4 + r) * 68 + et * 16 + l16] = acc[et][r];
    __syncthreads();

    const int row = tid >> 4, c0 = (tid & 15) * 4;
    f32x4 s = *(const f32x4*)&R[row * 68 + c0];
#pragma unroll
    for (int wv = 1; wv < 4; ++wv) s += *(const f32x4*)&R[wv * (16 * 68) + row * 68 + c0];
    s += *(const f32x4*)(bout + c0);
    *(f32x4*)(out + (size_t)(r0 + row) * 64 + c0) = s;
}

// ---------------------------------------------------------------------------
extern "C" void kernel_launch(void* const* d_in, const int* in_sizes, int n_in,
                              void* d_out, int out_size, void* d_ws, size_t ws_size,
                              hipStream_t stream)
{
    const float* values  = (const float*)d_in[0];
    const float* keys    = (const float*)d_in[1];
    const float* queries = (const float*)d_in[2];
    const float* Wv      = (const float*)d_in[3];
    const float* Wk      = (const float*)d_in[4];
    const float* Wq      = (const float*)d_in[5];
    const float* Wout    = (const float*)d_in[6];
    const float* bout    = (const float*)d_in[7];

    float* out  = (float*)d_out;                       // [N,S,64]
    float* attn = out + (size_t)N_ * S_ * D_;          // [N,H,S,S]

    const size_t nelem = (size_t)N_ * H_ * S_ * D_;    // 4,194,304
    unsigned short* qb   = (unsigned short*)d_ws;
    unsigned short* kb   = qb  + nelem;
    unsigned short* vtb  = kb  + nelem;
    unsigned short* catb = vtb + nelem;                // [N,S,H*D] bf16

    proj_kernel<<<dim3(N_ * H_ * (S_ / 64), 3), 256, 0, stream>>>(
        queries, keys, values, Wq, Wk, Wv, qb, kb, vtb);
    attn_kernel<<<N_ * H_ * (S_ / 32), 256, 0, stream>>>(qb, kb, vtb, attn, catb);
    outproj_kernel<<<(N_ * S_) / 16, 256, 0, stream>>>(catb, Wout, bout, out);
}

// Round 4
// 392.898 us; speedup vs baseline: 1.2285x; 1.2285x over previous
//
#include <hip/hip_runtime.h>

typedef __bf16 bf16x8 __attribute__((ext_vector_type(8)));
typedef __bf16 bf16x4 __attribute__((ext_vector_type(4)));
typedef float  f32x4  __attribute__((ext_vector_type(4)));

#define MFMA16(a, b, c) __builtin_amdgcn_mfma_f32_16x16x32_bf16((a), (b), (c), 0, 0, 0)

constexpr int N_ = 8, H_ = 8, S_ = 1024, D_ = 64;

// ---------------------------------------------------------------------------
// Kernel 1: per-head projections.  q[n,h,s,e] row-major bf16 (unchanged).
// K and V are now written FRAGMENT-BLOCKED so that every MFMA fragment load
// in attn_kernel is a fully-coalesced 1KB wave load (8 lines, 100% utilized)
// instead of a 16-line half-used scatter:
//   K'[nh][kt(64)][half(2)][quad][l16][8]   elem (key=kt*16+l16, e=half*32+quad*8+j)
//   V'[nh][ch(32)][et(4)][quad][l16][8]     elem (e=et*16+l16,  k=ch*32+quad*8+j)
// grid = (N*H*(S/64), 3), block 256.
// ---------------------------------------------------------------------------
__global__ __launch_bounds__(256) void proj_kernel(
    const float* __restrict__ Xq, const float* __restrict__ Xk,
    const float* __restrict__ Xv,
    const float* __restrict__ Wq, const float* __restrict__ Wk,
    const float* __restrict__ Wv,
    unsigned short* __restrict__ qb_, unsigned short* __restrict__ kb_,
    unsigned short* __restrict__ vtb_)
{
    __shared__ __bf16 T[64 * 72];            // 9.2 KB staging tile

    const int which = blockIdx.y;
    const float* X = (which == 0) ? Xq : (which == 1) ? Xk : Xv;
    const float* W = (which == 0) ? Wq : (which == 1) ? Wk : Wv;

    const int b   = blockIdx.x;              // 0..1023
    const int st  = b & 15;
    const int h   = (b >> 4) & 7;
    const int n   = b >> 7;
    const int s0  = st * 64;
    const int nh  = n * H_ + h;
    const int tid = threadIdx.x;
    const int w = tid >> 6, lane = tid & 63;
    const int l16 = lane & 15, quad = lane >> 4;

    const float* xrow = X + (size_t)(n * S_ + s0 + w * 16 + l16) * D_;
    bf16x8 a[2];
#pragma unroll
    for (int half = 0; half < 2; ++half) {
        const float* p = xrow + half * 32 + quad * 8;
        f32x4 x0 = *(const f32x4*)p;
        f32x4 x1 = *(const f32x4*)(p + 4);
#pragma unroll
        for (int j = 0; j < 4; ++j) { a[half][j] = (__bf16)x0[j]; a[half][4 + j] = (__bf16)x1[j]; }
    }

#pragma unroll
    for (int et = 0; et < 4; ++et) {
        const int e0 = et * 16;
        f32x4 acc = {0.f, 0.f, 0.f, 0.f};
#pragma unroll
        for (int half = 0; half < 2; ++half) {
            const float* wp = W + ((size_t)(h * 64 + e0 + l16)) * 64 + half * 32 + quad * 8;
            f32x4 x0 = *(const f32x4*)wp;
            f32x4 x1 = *(const f32x4*)(wp + 4);
            bf16x8 bf;
#pragma unroll
            for (int j = 0; j < 4; ++j) { bf[j] = (__bf16)x0[j]; bf[4 + j] = (__bf16)x1[j]; }
            acc = MFMA16(a[half], bf, acc);
        }
#pragma unroll
        for (int r = 0; r < 4; ++r) {
            const int sl = w * 16 + quad * 4 + r;
            const int e  = e0 + l16;
            const __bf16 v = (__bf16)acc[r];
            if (which == 2) T[e * 72 + sl] = v;     // transposed tile [e][s]
            else            T[sl * 72 + e] = v;     // [s][e]
        }
    }
    __syncthreads();

    if (which == 0) {
        // Q: plain [S][64] coalesced write
        const int row = tid >> 2, seg = tid & 3;
        const bf16x8 d0 = *(const bf16x8*)&T[row * 72 + seg * 16];
        const bf16x8 d1 = *(const bf16x8*)&T[row * 72 + seg * 16 + 8];
        __bf16* dst = (__bf16*)qb_ + ((size_t)nh * S_ + s0 + row) * D_ + seg * 16;
        *(bf16x8*)dst = d0;
        *(bf16x8*)(dst + 8) = d1;
    } else if (which == 1) {
        // K fragment-blocked: 512 16B chunks; c -> ktl(2b) | h2(1b) | ll(6b)
#pragma unroll
        for (int cc = 0; cc < 2; ++cc) {
            const int c   = tid + cc * 256;
            const int ktl = c >> 7;
            const int h2  = (c >> 6) & 1;
            const int ll  = c & 63;
            const bf16x8 d = *(const bf16x8*)&T[(ktl * 16 + (ll & 15)) * 72 + h2 * 32 + (ll >> 4) * 8];
            __bf16* dst = (__bf16*)kb_ +
                (((size_t)(nh * 64 + st * 4 + ktl) * 2 + h2) * 512 + ll * 8);
            *(bf16x8*)dst = d;
        }
    } else {
        // V fragment-blocked: 512 16B chunks; c -> chl(1b) | et(2b) | lv(6b)
#pragma unroll
        for (int cc = 0; cc < 2; ++cc) {
            const int c   = tid + cc * 256;
            const int chl = c >> 8;
            const int et  = (c >> 6) & 3;
            const int lv  = c & 63;
            const bf16x8 d = *(const bf16x8*)&T[(et * 16 + (lv & 15)) * 72 + chl * 32 + (lv >> 4) * 8];
            __bf16* dst = (__bf16*)vtb_ + (size_t)nh * 65536 +
                ((size_t)(st * 2 + chl) * 2048 + et * 512 + lv * 8);
            *(bf16x8*)dst = d;
        }
    }
}

// ---------------------------------------------------------------------------
// Kernel 2: attention.  Structure identical to round 3 (grid 2048, 2-way
// K-split, XCD swizzle, bpermute in-register P transpose); all K/V fragment
// loads are now contiguous 1KB wave loads from the blocked layouts.
// ---------------------------------------------------------------------------
__global__ __launch_bounds__(256, 8) void attn_kernel(
    const unsigned short* __restrict__ qb_, const unsigned short* __restrict__ kb_,
    const unsigned short* __restrict__ vtb_,
    float* __restrict__ attn_out, unsigned short* __restrict__ catb_)
{
    __shared__ float Sred[4 * 16];           // per-wave partial denominators
    __shared__ float Ored[2 * 16 * 68];      // kw=1 waves' PV partials (8.7 KB)

    const __bf16* qb  = (const __bf16*)qb_;
    const __bf16* kb  = (const __bf16*)kb_;
    const __bf16* vtb = (const __bf16*)vtb_;
    __bf16* catb = (__bf16*)catb_;

    // XCD swizzle: XCD x gets logical blocks [x*256, (x+1)*256) = 8 heads.
    const int bid = blockIdx.x;              // 0..2047
    const int b   = (bid & 7) * 256 + (bid >> 3);
    const int qt  = b & 31;
    const int h   = (b >> 5) & 7;
    const int n   = b >> 8;
    const int nh  = n * H_ + h;
    const int q0  = qt * 32;

    const int tid = threadIdx.x;
    const int w = tid >> 6, lane = tid & 63;
    const int l16 = lane & 15, quad = lane >> 4;
    const int rw = w & 1;                    // row half (0: rows 0-15, 1: 16-31)
    const int kw = w >> 1;                   // key half
    const int k0 = kw * 512;

    // persistent Q fragments (row q0 + rw*16 + l16, two embed-halves)
    const __bf16* qbase = qb + ((size_t)(nh * S_ + q0 + rw * 16 + l16)) * D_;
    const bf16x8 aq0 = *(const bf16x8*)(qbase + quad * 8);
    const bf16x8 aq1 = *(const bf16x8*)(qbase + 32 + quad * 8);

    // fragment-blocked K base for this wave's 32 key-tiles
    const __bf16* kfrag = kb + ((size_t)(nh * 64 + kw * 32)) * 1024 + lane * 8;

    // ---- pass 1: partial row sums of exp(qk/8) over this wave's 512 keys.
    float ssum = 0.f;
#pragma unroll 4
    for (int kt = 0; kt < 32; ++kt) {
        const __bf16* kp = kfrag + kt * 1024;
        const bf16x8 b0 = *(const bf16x8*)kp;
        const bf16x8 b1 = *(const bf16x8*)(kp + 512);
        f32x4 c = {0.f, 0.f, 0.f, 0.f};
        c = MFMA16(b0, aq0, c);
        c = MFMA16(b1, aq1, c);
#pragma unroll
        for (int r = 0; r < 4; ++r) ssum += __expf(c[r] * 0.125f);
    }
    ssum += __shfl_xor(ssum, 16);
    ssum += __shfl_xor(ssum, 32);
    if (lane < 16) Sred[w * 16 + lane] = ssum;
    __syncthreads();
    const float inv = 1.0f / (Sred[w * 16 + l16] + Sred[(w ^ 2) * 16 + l16]);

    // ---- pass 2: recompute QK, in-register transpose, attn store, partial PV
    float* abase = attn_out + ((size_t)(nh * S_ + q0 + rw * 16 + l16)) * S_ + k0;
    const __bf16* vfrag = vtb + (size_t)nh * 65536 + (size_t)kw * 16 * 2048 + lane * 8;

    const int lo_addr = (((quad & 1) * 2) * 16 + l16) * 4;
    const int hi_addr = lo_addr + 64;
    const bool hiq = (quad & 2) != 0;        // target tile = quad>>1

    f32x4 acc[4] = {{0.f,0.f,0.f,0.f},{0.f,0.f,0.f,0.f},{0.f,0.f,0.f,0.f},{0.f,0.f,0.f,0.f}};

#pragma unroll 2
    for (int ch = 0; ch < 16; ++ch) {
        unsigned Wt[2][2];
#pragma unroll
        for (int t = 0; t < 2; ++t) {
            const int kt = ch * 2 + t;
            const __bf16* kp = kfrag + kt * 1024;
            const bf16x8 b0 = *(const bf16x8*)kp;
            const bf16x8 b1 = *(const bf16x8*)(kp + 512);
            f32x4 c = {0.f, 0.f, 0.f, 0.f};
            c = MFMA16(b0, aq0, c);
            c = MFMA16(b1, aq1, c);
            float p[4];
#pragma unroll
            for (int r = 0; r < 4; ++r) p[r] = __expf(c[r] * 0.125f) * inv;
#pragma unroll
            for (int pr = 0; pr < 2; ++pr) {
                const __bf16 ha = (__bf16)p[2 * pr], hb = (__bf16)p[2 * pr + 1];
                const unsigned ua = *(const unsigned short*)&ha;
                const unsigned ub = *(const unsigned short*)&hb;
                Wt[t][pr] = ua | (ub << 16);
            }
        }
        // in-register transpose: build PV A-fragment P[q=l16][k=quad*8+j]
        const int s00 = __builtin_amdgcn_ds_bpermute(lo_addr, (int)Wt[0][0]);
        const int s10 = __builtin_amdgcn_ds_bpermute(lo_addr, (int)Wt[1][0]);
        const int s01 = __builtin_amdgcn_ds_bpermute(lo_addr, (int)Wt[0][1]);
        const int s11 = __builtin_amdgcn_ds_bpermute(lo_addr, (int)Wt[1][1]);
        const int s02 = __builtin_amdgcn_ds_bpermute(hi_addr, (int)Wt[0][0]);
        const int s12 = __builtin_amdgcn_ds_bpermute(hi_addr, (int)Wt[1][0]);
        const int s03 = __builtin_amdgcn_ds_bpermute(hi_addr, (int)Wt[0][1]);
        const int s13 = __builtin_amdgcn_ds_bpermute(hi_addr, (int)Wt[1][1]);
        union { bf16x8 v; unsigned u[4]; } pf;
        pf.u[0] = (unsigned)(hiq ? s10 : s00);
        pf.u[1] = (unsigned)(hiq ? s11 : s01);
        pf.u[2] = (unsigned)(hiq ? s12 : s02);
        pf.u[3] = (unsigned)(hiq ? s13 : s03);

        // PV: acc[et] += P(16x32) * V(32x16); V loads contiguous 1KB
#pragma unroll
        for (int et = 0; et < 4; ++et) {
            const bf16x8 bv = *(const bf16x8*)(vfrag + ch * 2048 + et * 512);
            acc[et] = MFMA16(pf.v, bv, acc[et]);
        }

        // attn fp32 store: row q0+rw*16+l16, cols k0+ch*32+quad*8 (2x16B)
        f32x4 f0, f1;
#pragma unroll
        for (int j = 0; j < 4; ++j) { f0[j] = (float)pf.v[j]; f1[j] = (float)pf.v[4 + j]; }
        float* ap = abase + ch * 32 + quad * 8;
        *(f32x4*)ap = f0;
        *(f32x4*)(ap + 4) = f1;
    }

    // ---- cross-wave PV reduction: kw=1 waves publish, kw=0 waves finish ----
    __syncthreads();                          // Sred fully consumed before reuse
    if (kw == 1) {
#pragma unroll
        for (int et = 0; et < 4; ++et)
#pragma unroll
            for (int r = 0; r < 4; ++r)
                Ored[rw * (16 * 68) + (quad * 4 + r) * 68 + et * 16 + l16] = acc[et][r];
    }
    __syncthreads();
    if (kw == 0) {
#pragma unroll
        for (int r = 0; r < 4; ++r) {
            const int s = q0 + rw * 16 + quad * 4 + r;
            __bf16* cp = catb + ((size_t)n * S_ + s) * (H_ * D_) + h * D_ + l16;
#pragma unroll
            for (int et = 0; et < 4; ++et) {
                const float o = acc[et][r] +
                    Ored[rw * (16 * 68) + (quad * 4 + r) * 68 + et * 16 + l16];
                cp[et * 16] = (__bf16)o;
            }
        }
    }
}

// ---------------------------------------------------------------------------
// Kernel 3: out = cat @ Wout^T + bout.  (unchanged — known good)
// ---------------------------------------------------------------------------
__global__ __launch_bounds__(256) void outproj_kernel(
    const unsigned short* __restrict__ catb_, const float* __restrict__ Wout,
    const float* __restrict__ bout, float* __restrict__ out)
{
    __shared__ float R[4 * 16 * 68];         // 17.4 KB partials

    const __bf16* catb = (const __bf16*)catb_;
    const int r0  = blockIdx.x * 16;
    const int tid = threadIdx.x;
    const int w = tid >> 6, lane = tid & 63;
    const int l16 = lane & 15, quad = lane >> 4;
    const int k0 = w * 128;

    const __bf16* arow  = catb + (size_t)(r0 + l16) * 512 + k0 + quad * 8;
    const float*  wbase = Wout + (size_t)l16 * 512 + k0 + quad * 8;

    f32x4 acc[4] = {{0.f,0.f,0.f,0.f},{0.f,0.f,0.f,0.f},{0.f,0.f,0.f,0.f},{0.f,0.f,0.f,0.f}};

#pragma unroll
    for (int kc = 0; kc < 4; ++kc) {
        const bf16x8 af = *(const bf16x8*)(arow + kc * 32);
#pragma unroll
        for (int et = 0; et < 4; ++et) {
            const float* wp = wbase + (size_t)et * 16 * 512 + kc * 32;
            f32x4 x0 = *(const f32x4*)wp;
            f32x4 x1 = *(const f32x4*)(wp + 4);
            bf16x8 bf;
#pragma unroll
            for (int j = 0; j < 4; ++j) { bf[j] = (__bf16)x0[j]; bf[4 + j] = (__bf16)x1[j]; }
            acc[et] = MFMA16(af, bf, acc[et]);
        }
    }
#pragma unroll
    for (int et = 0; et < 4; ++et)
#pragma unroll
        for (int r = 0; r < 4; ++r)
            R[w * (16 * 68) + (quad * 4 + r) * 68 + et * 16 + l16] = acc[et][r];
    __syncthreads();

    const int row = tid >> 4, c0 = (tid & 15) * 4;
    f32x4 s = *(const f32x4*)&R[row * 68 + c0];
#pragma unroll
    for (int wv = 1; wv < 4; ++wv) s += *(const f32x4*)&R[wv * (16 * 68) + row * 68 + c0];
    s += *(const f32x4*)(bout + c0);
    *(f32x4*)(out + (size_t)(r0 + row) * 64 + c0) = s;
}

// ---------------------------------------------------------------------------
extern "C" void kernel_launch(void* const* d_in, const int* in_sizes, int n_in,
                              void* d_out, int out_size, void* d_ws, size_t ws_size,
                              hipStream_t stream)
{
    const float* values  = (const float*)d_in[0];
    const float* keys    = (const float*)d_in[1];
    const float* queries = (const float*)d_in[2];
    const float* Wv      = (const float*)d_in[3];
    const float* Wk      = (const float*)d_in[4];
    const float* Wq      = (const float*)d_in[5];
    const float* Wout    = (const float*)d_in[6];
    const float* bout    = (const float*)d_in[7];

    float* out  = (float*)d_out;                       // [N,S,64]
    float* attn = out + (size_t)N_ * S_ * D_;          // [N,H,S,S]

    const size_t nelem = (size_t)N_ * H_ * S_ * D_;    // 4,194,304
    unsigned short* qb   = (unsigned short*)d_ws;
    unsigned short* kb   = qb  + nelem;
    unsigned short* vtb  = kb  + nelem;
    unsigned short* catb = vtb + nelem;                // [N,S,H*D] bf16

    proj_kernel<<<dim3(N_ * H_ * (S_ / 64), 3), 256, 0, stream>>>(
        queries, keys, values, Wq, Wk, Wv, qb, kb, vtb);
    attn_kernel<<<N_ * H_ * (S_ / 32), 256, 0, stream>>>(qb, kb, vtb, attn, catb);
    outproj_kernel<<<(N_ * S_) / 16, 256, 0, stream>>>(catb, Wout, bout, out);
}